// Round 3
// baseline (74.059 us; speedup 1.0000x reference)
//
#include <hip/hip_runtime.h>
#include <hip/hip_bf16.h>

// Problem constants (from reference)
#define BATCH 16
#define HH 1024
#define WW 2048
#define HWPIX (HH * WW)            // 2,097,152 pixels per batch
#define NID 255                    // ids 101..355 -> index 0..254

#define THREADS 1024
#define SLICES 32                  // blocks per batch; 16*32 = 512 blocks = 2/CU
#define PIX_PER_BLOCK (HWPIX / SLICES)        // 65536 (32 rows of 2048)
#define ROWS_PER_BLOCK (PIX_PER_BLOCK / WW)   // 32
#define ITERS (PIX_PER_BLOCK / (THREADS * 4)) // 16
#define NCOL 32                    // columns per id, shared by lane pairs

typedef unsigned long long u64;

// Per-column packing (a column absorbs 2 lanes x 64 pixels = <=128 pixels):
//   bits [0,24)  = sum_x      (max 128*2047 = 262,016 < 2^24)
//   bits [24,40) = sum_y_rel  (max 128*31   = 3,968   < 2^16)
//   bits [40,..) = count      (max 128)
// All fields overflow-free by construction -> single u64 atomic add per pixel.
// Same-address collision between paired lanes only when ids match (~1/356).

__global__ __launch_bounds__(THREADS, 8) void accum_kernel(
    const float* __restrict__ logits, const int* __restrict__ label,
    unsigned* __restrict__ g_cnt, unsigned* __restrict__ g_sx,
    unsigned* __restrict__ g_sy, double* __restrict__ g_exp)
{
    __shared__ u64 table[NID * NCOL];      // 65,280 B -> 2 blocks/CU
    __shared__ double exp_lds[16];

    const int tid  = threadIdx.x;
    const int lane = tid & 63;
    const int col  = lane >> 1;            // lane-pair column
    const int batch = blockIdx.x >> 5;
    const int slice = blockIdx.x & 31;

    for (int i = tid; i < NID * NCOL; i += THREADS) table[i] = 0ull;
    __syncthreads();

    const float4* lg4 = (const float4*)logits + (size_t)batch * (HWPIX / 4) + slice * (PIX_PER_BLOCK / 4);
    const int4*   lb4 = (const int4*)label   + (size_t)batch * (HWPIX / 4) + slice * (PIX_PER_BLOCK / 4);

    float es = 0.f;
#pragma unroll 4
    for (int i = 0; i < ITERS; ++i) {
        const int g = i * THREADS + tid;          // float4-group within slice
        const float4 f  = lg4[g];
        const int4   lb = lb4[g];
        es += __expf(f.x) + __expf(f.y) + __expf(f.z) + __expf(f.w);
        const int p0 = g << 2;                    // pixel index within slice
        const int yr = p0 >> 11;                  // row within slice (0..31)
        const int x0 = p0 & 2047;
        const u64 base = ((u64)1 << 40) | ((u64)yr << 24);
        if (lb.x > 100) atomicAdd(&table[(lb.x - 101) * NCOL + col], base | (u64)(x0 + 0));
        if (lb.y > 100) atomicAdd(&table[(lb.y - 101) * NCOL + col], base | (u64)(x0 + 1));
        if (lb.z > 100) atomicAdd(&table[(lb.z - 101) * NCOL + col], base | (u64)(x0 + 2));
        if (lb.w > 100) atomicAdd(&table[(lb.w - 101) * NCOL + col], base | (u64)(x0 + 3));
    }

    // exp partial: wave shuffle reduce -> LDS -> ONE f64 atomic per block
    for (int off = 32; off > 0; off >>= 1) es += __shfl_down(es, off, 64);
    if (lane == 0) exp_lds[tid >> 6] = (double)es;
    __syncthreads();
    if (tid == 0) {
        double t = 0.0;
        for (int w = 0; w < 16; ++w) t += exp_lds[w];
        atomicAdd(g_exp, t);
    }

    // flush: thread id (<255) sums its id's 32 lane-pair columns, 3 u32 atomics out
    if (tid < NID) {
        unsigned cnt = 0, sx = 0, syr = 0;
        const u64* colp = &table[tid * NCOL];
        for (int l = 0; l < NCOL; ++l) {
            const u64 v = colp[l];
            cnt += (unsigned)(v >> 40);
            syr += (unsigned)((v >> 24) & 0xFFFFu);
            sx  += (unsigned)(v & 0xFFFFFFu);
        }
        if (cnt) {
            const unsigned base_row = slice * ROWS_PER_BLOCK;
            atomicAdd(&g_cnt[batch * NID + tid], cnt);
            atomicAdd(&g_sx [batch * NID + tid], sx);
            atomicAdd(&g_sy [batch * NID + tid], syr + base_row * cnt);
        }
    }
}

__global__ __launch_bounds__(256) void finalize_kernel(
    const float* __restrict__ logits, const unsigned* __restrict__ g_cnt,
    const unsigned* __restrict__ g_sx, const unsigned* __restrict__ g_sy,
    const double* __restrict__ g_exp, float* __restrict__ out)
{
    const int tid = threadIdx.x;
    float s = 0.f;
    if (tid < NID) {                    // id = 101 + tid
        for (int b = 0; b < BATCH; ++b) {
            const unsigned cnt = g_cnt[b * NID + tid];
            if (cnt) {
                const float fc = (float)cnt;
                // identical f32 divide + truncation as the reference
                const int cx = (int)((float)g_sx[b * NID + tid] / fc);
                const int cy = (int)((float)g_sy[b * NID + tid] / fc);
                s += logits[(size_t)b * HWPIX + (size_t)cy * WW + cx];
            }
        }
    }
    __shared__ float red[256];
    red[tid] = s;
    __syncthreads();
    for (int off = 128; off > 0; off >>= 1) {
        if (tid < off) red[tid] += red[tid + off];
        __syncthreads();
    }
    if (tid == 0) {
        const double int_loss = *g_exp / (double)((double)BATCH * (double)HWPIX);
        out[0] = (float)(int_loss - (double)red[0] / (double)BATCH);
    }
}

extern "C" void kernel_launch(void* const* d_in, const int* in_sizes, int n_in,
                              void* d_out, int out_size, void* d_ws, size_t ws_size,
                              hipStream_t stream) {
    const float* logits = (const float*)d_in[0];
    const int*   label  = (const int*)d_in[1];
    float* out = (float*)d_out;

    unsigned* g_cnt = (unsigned*)d_ws;
    unsigned* g_sx  = g_cnt + BATCH * NID;
    unsigned* g_sy  = g_sx  + BATCH * NID;
    double*   g_exp = (double*)(g_sy + BATCH * NID);   // 48,960 B offset, 8-aligned

    // zero accumulators every call (harness does not re-poison between replays)
    hipMemsetAsync(d_ws, 0, (size_t)BATCH * NID * 3 * sizeof(unsigned) + sizeof(double), stream);

    accum_kernel<<<BATCH * SLICES, THREADS, 0, stream>>>(logits, label, g_cnt, g_sx, g_sy, g_exp);
    finalize_kernel<<<1, 256, 0, stream>>>(logits, g_cnt, g_sx, g_sy, g_exp, out);
}